// Round 2
// baseline (2208.248 us; speedup 1.0000x reference)
//
#include <hip/hip_runtime.h>
#include <hip/hip_bf16.h>
#include <math.h>

#define B_TOK 8192
#define D_DIM 1024
#define H_DIM 4096
#define E_NUM 8
#define NPAIR (B_TOK * 2)

typedef __bf16 bf16x8 __attribute__((ext_vector_type(8)));
typedef float f32x4 __attribute__((ext_vector_type(4)));
typedef unsigned short us4 __attribute__((ext_vector_type(4)));

__device__ __forceinline__ unsigned short f2bf(float f) {
  union { float f; unsigned u; } v; v.f = f;
  unsigned r = v.u + 0x7FFFu + ((v.u >> 16) & 1u);
  return (unsigned short)(r >> 16);
}

__device__ __forceinline__ void gload16(const void* g, void* l) {
  __builtin_amdgcn_global_load_lds(
      (const __attribute__((address_space(1))) void*)g,
      (__attribute__((address_space(3))) void*)l, 16, 0, 0);
}

// ---------------- x fp32 -> bf16 ----------------
__global__ void k_convert_x(const float* __restrict__ x, unsigned short* __restrict__ xb) {
  int i = (blockIdx.x * 256 + threadIdx.x) * 4;
  float4 v = *(const float4*)(x + i);
  us4 o;
  o[0] = f2bf(v.x); o[1] = f2bf(v.y); o[2] = f2bf(v.z); o[3] = f2bf(v.w);
  *(us4*)(xb + i) = o;
}

// -------- (E, rows, cols) fp32 -> (E, cols, rows) bf16 --------
__global__ void k_transpose_bf16(const float* __restrict__ in, unsigned short* __restrict__ out,
                                 int rows, int cols) {
  __shared__ float t[32][33];
  const float* ine = in + (size_t)blockIdx.z * rows * cols;
  unsigned short* oute = out + (size_t)blockIdx.z * rows * cols;
  int c0 = blockIdx.x * 32, r0 = blockIdx.y * 32;
  int tx = threadIdx.x, ty = threadIdx.y;
#pragma unroll
  for (int j = 0; j < 32; j += 8)
    t[ty + j][tx] = ine[(size_t)(r0 + ty + j) * cols + c0 + tx];
  __syncthreads();
#pragma unroll
  for (int j = 0; j < 32; j += 8)
    oute[(size_t)(c0 + ty + j) * rows + r0 + tx] = f2bf(t[tx][ty + j]);
}

// ---------------- router: logits, top-2, softmax ----------------
__global__ void k_router(const float* __restrict__ x, const float* __restrict__ wg,
                         const float* __restrict__ bg, int* __restrict__ tidx,
                         float* __restrict__ tgate, int* __restrict__ cnt) {
  int wid = threadIdx.x >> 6, lane = threadIdx.x & 63;
  int t = blockIdx.x * 4 + wid;
  float acc[E_NUM];
#pragma unroll
  for (int e = 0; e < E_NUM; e++) acc[e] = 0.f;
  const float* xr = x + (size_t)t * D_DIM;
  for (int i = lane; i < D_DIM; i += 64) {
    float xv = xr[i];
#pragma unroll
    for (int e = 0; e < E_NUM; e++) acc[e] += xv * wg[e * D_DIM + i];
  }
#pragma unroll
  for (int e = 0; e < E_NUM; e++) {
#pragma unroll
    for (int off = 32; off; off >>= 1) acc[e] += __shfl_xor(acc[e], off);
  }
  if (lane == 0) {
    float v[E_NUM];
#pragma unroll
    for (int e = 0; e < E_NUM; e++) v[e] = acc[e] + bg[e];
    int i0 = 0; float v0 = v[0];
#pragma unroll
    for (int e = 1; e < E_NUM; e++) if (v[e] > v0) { v0 = v[e]; i0 = e; }
    int i1 = -1; float v1 = -1e30f;
#pragma unroll
    for (int e = 0; e < E_NUM; e++) if (e != i0 && v[e] > v1) { v1 = v[e]; i1 = e; }
    float g0 = 1.f / (1.f + expf(v1 - v0));
    float g1 = 1.f - g0;
    tidx[2 * t] = i0; tidx[2 * t + 1] = i1;
    tgate[2 * t] = g0; tgate[2 * t + 1] = g1;
    atomicAdd(cnt + i0, 1);
    atomicAdd(cnt + i1, 1);
  }
}

__global__ void k_prefix(const int* __restrict__ cnt, int* __restrict__ eoff,
                         int* __restrict__ cursor) {
  if (threadIdx.x == 0) {
    int a = 0;
    for (int e = 0; e < E_NUM; e++) { eoff[e] = a; cursor[e] = a; a += cnt[e]; }
    eoff[E_NUM] = a;
  }
}

__global__ void k_scatter(const int* __restrict__ tidx, const float* __restrict__ tgate,
                          int* __restrict__ cursor, int* __restrict__ ptok,
                          float* __restrict__ pgate) {
  int t = blockIdx.x * 256 + threadIdx.x;
#pragma unroll
  for (int k = 0; k < 2; k++) {
    int e = tidx[2 * t + k];
    int p = atomicAdd(cursor + e, 1);
    ptok[p] = t;
    pgate[p] = tgate[2 * t + k];
  }
}

// ---------------- grouped GEMM, 256x256 tile, double-buffered ----------------
// MODE 1: A = xb gathered via ptok, out = relu(A@B^T + b1) -> Hbuf (bf16)
// MODE 2: A = Hbuf rows direct,   out = (A@B^T + b2)*gate atomicAdd-> Out
// Grid = E * MT_MAX * NT (nt innermost), XCD chunk-swizzled (nwg % 8 == 0).
template <int KDIM, int NDIM, int MODE>
__global__ __launch_bounds__(512, 2) void k_gemm(
    const unsigned short* __restrict__ A, const unsigned short* __restrict__ Bt,
    const float* __restrict__ bias, const int* __restrict__ eoff,
    const int* __restrict__ ptok, const float* __restrict__ pgate,
    unsigned short* __restrict__ Hout, float* __restrict__ Out) {
  constexpr int NT = NDIM / 256;
  constexpr int MT_MAX = NPAIR / 256;
  // XCD chunk swizzle: blocks with the same (bid % 8) run on one XCD; give
  // them a contiguous tile range (one expert's tiles per XCD when balanced).
  int nwg = gridDim.x;
  int bid = blockIdx.x;
  int tile = (bid & 7) * (nwg >> 3) + (bid >> 3);
  int e = tile / (MT_MAX * NT);
  int rem = tile - e * (MT_MAX * NT);
  int mt = rem / NT;
  int nt = rem - mt * NT;
  int off = eoff[e];
  int cnt = eoff[e + 1] - off;
  int m0 = mt * 256;
  if (m0 >= cnt) return;

  // [buf][A=0/B=1][256 rows][32 shorts]
  __shared__ unsigned short lds[2][2][256 * 32];

  int tid = threadIdx.x;
  int w = tid >> 6, lane = tid & 63;
  int wm = w >> 2, wn = w & 3;  // 2 x 4 wave grid, each wave: 128 x 64 output

  // staging: chunk q = w*2+c covers rows q*16..q*16+15 of the 256-row tile;
  // lane covers row q*16+(lane>>2), 16B segment (lane&3). LDS dst is
  // wave-uniform base + lane*16 (HW rule), layout linear [row][32 shorts].
  const unsigned short* aSrc[2];
  const unsigned short* bSrc[2];
#pragma unroll
  for (int c = 0; c < 2; c++) {
    int q = w * 2 + c;
    int lrow = q * 16 + (lane >> 2);
    int arow = m0 + lrow;
    int ar = (arow < cnt) ? arow : (cnt - 1);
    size_t grow;
    if (MODE == 1) grow = (size_t)ptok[off + ar];
    else grow = (size_t)(off + ar);
    aSrc[c] = A + grow * KDIM + (lane & 3) * 8;
    int nrow = nt * 256 + q * 16 + (lane >> 2);
    bSrc[c] = Bt + (size_t)e * NDIM * KDIM + (size_t)nrow * KDIM + (lane & 3) * 8;
  }

  f32x4 acc[8][4] = {};

#define STAGE(buf, k0)                                          \
  {                                                             \
    _Pragma("unroll")                                           \
    for (int c = 0; c < 2; c++) {                               \
      int q = w * 2 + c;                                        \
      gload16(aSrc[c] + (k0), &lds[buf][0][q * 512]);           \
      gload16(bSrc[c] + (k0), &lds[buf][1][q * 512]);           \
    }                                                           \
  }

#define COMPUTE(buf)                                                        \
  {                                                                         \
    bf16x8 aF[8], bF[4];                                                    \
    _Pragma("unroll")                                                       \
    for (int m = 0; m < 8; m++) {                                           \
      int row = wm * 128 + m * 16 + (lane & 15);                            \
      aF[m] = *(const bf16x8*)&lds[buf][0][row * 32 + (lane >> 4) * 8];     \
    }                                                                       \
    _Pragma("unroll")                                                       \
    for (int n = 0; n < 4; n++) {                                           \
      int row = wn * 64 + n * 16 + (lane & 15);                             \
      bF[n] = *(const bf16x8*)&lds[buf][1][row * 32 + (lane >> 4) * 8];     \
    }                                                                       \
    _Pragma("unroll")                                                       \
    for (int m = 0; m < 8; m++)                                             \
      _Pragma("unroll")                                                     \
      for (int n = 0; n < 4; n++)                                           \
        acc[m][n] =                                                         \
            __builtin_amdgcn_mfma_f32_16x16x32_bf16(aF[m], bF[n], acc[m][n], 0, 0, 0); \
  }

  // prologue: fill buf 0
  STAGE(0, 0);
  __syncthreads();
  int cur = 0;
  // steady state: issue next-tile stage BEFORE computing current tile, so the
  // global_load_lds latency hides under the 32 MFMAs; one barrier per K-step.
  for (int k0 = 32; k0 < KDIM; k0 += 32) {
    if (cur == 0) {
      STAGE(1, k0);
      COMPUTE(0);
    } else {
      STAGE(0, k0);
      COMPUTE(1);
    }
    __syncthreads();  // drains vmcnt+lgkmcnt, next buffer ready
    cur ^= 1;
  }
  if (cur == 0) COMPUTE(0) else COMPUTE(1);

#undef STAGE
#undef COMPUTE

  // epilogue: C/D map col=lane&15, row=(lane>>4)*4+r
#pragma unroll
  for (int m = 0; m < 8; m++) {
    int lrowb = wm * 128 + m * 16 + (lane >> 4) * 4;
#pragma unroll
    for (int r = 0; r < 4; r++) {
      int arow = m0 + lrowb + r;
      if (arow < cnt) {
        if constexpr (MODE == 1) {
          size_t rowbase = (size_t)(off + arow) * NDIM;
#pragma unroll
          for (int n = 0; n < 4; n++) {
            int col = nt * 256 + wn * 64 + n * 16 + (lane & 15);
            float v = acc[m][n][r] + bias[e * NDIM + col];
            v = v > 0.f ? v : 0.f;
            Hout[rowbase + col] = f2bf(v);
          }
        } else {
          int tok = ptok[off + arow];
          float g = pgate[off + arow];
#pragma unroll
          for (int n = 0; n < 4; n++) {
            int col = nt * 256 + wn * 64 + n * 16 + (lane & 15);
            float v = (acc[m][n][r] + bias[e * NDIM + col]) * g;
            atomicAdd(Out + (size_t)tok * D_DIM + col, v);
          }
        }
      }
    }
  }
}

extern "C" void kernel_launch(void* const* d_in, const int* in_sizes, int n_in,
                              void* d_out, int out_size, void* d_ws, size_t ws_size,
                              hipStream_t stream) {
  const float* x  = (const float*)d_in[0];
  const float* wg = (const float*)d_in[1];
  const float* bg = (const float*)d_in[2];
  const float* w1 = (const float*)d_in[3];
  const float* b1 = (const float*)d_in[4];
  const float* w2 = (const float*)d_in[5];
  const float* b2 = (const float*)d_in[6];
  float* out = (float*)d_out;

  char* ws = (char*)d_ws;
  unsigned short* xb = (unsigned short*)ws;   ws += (size_t)B_TOK * D_DIM * 2;
  unsigned short* w1t = (unsigned short*)ws;  ws += (size_t)E_NUM * D_DIM * H_DIM * 2;
  unsigned short* w2t = (unsigned short*)ws;  ws += (size_t)E_NUM * D_DIM * H_DIM * 2;
  unsigned short* Hbuf = (unsigned short*)ws; ws += (size_t)NPAIR * H_DIM * 2;
  int* tidx = (int*)ws;    ws += (size_t)NPAIR * 4;
  float* tgate = (float*)ws; ws += (size_t)NPAIR * 4;
  int* ptok = (int*)ws;    ws += (size_t)NPAIR * 4;
  float* pgate = (float*)ws; ws += (size_t)NPAIR * 4;
  int* meta = (int*)ws;  // cnt[8] | eoff[9] | cursor[8]
  int* cnt = meta;
  int* eoff = meta + 8;
  int* cursor = meta + 17;

  hipMemsetAsync(meta, 0, 32 * sizeof(int), stream);
  hipMemsetAsync(out, 0, (size_t)out_size * sizeof(float), stream);

  k_convert_x<<<(B_TOK * D_DIM) / 1024, 256, 0, stream>>>(x, xb);
  dim3 tb(32, 8);
  k_transpose_bf16<<<dim3(H_DIM / 32, D_DIM / 32, E_NUM), tb, 0, stream>>>(w1, w1t, D_DIM, H_DIM);
  k_transpose_bf16<<<dim3(D_DIM / 32, H_DIM / 32, E_NUM), tb, 0, stream>>>(w2, w2t, H_DIM, D_DIM);
  k_router<<<B_TOK / 4, 256, 0, stream>>>(x, wg, bg, tidx, tgate, cnt);
  k_prefix<<<1, 64, 0, stream>>>(cnt, eoff, cursor);
  k_scatter<<<B_TOK / 256, 256, 0, stream>>>(tidx, tgate, cursor, ptok, pgate);
  k_gemm<D_DIM, H_DIM, 1><<<E_NUM * (NPAIR / 256) * (H_DIM / 256), 512, 0, stream>>>(
      xb, w1t, b1, eoff, ptok, pgate, Hbuf, nullptr);
  k_gemm<H_DIM, D_DIM, 2><<<E_NUM * (NPAIR / 256) * (D_DIM / 256), 512, 0, stream>>>(
      Hbuf, w2t, b2, eoff, ptok, pgate, nullptr, out);
}

// Round 3
// 911.306 us; speedup vs baseline: 2.4232x; 2.4232x over previous
//
#include <hip/hip_runtime.h>
#include <hip/hip_bf16.h>
#include <math.h>

#define B_TOK 8192
#define D_DIM 1024
#define H_DIM 4096
#define E_NUM 8
#define NPAIR (B_TOK * 2)

typedef __bf16 bf16x8 __attribute__((ext_vector_type(8)));
typedef float f32x4 __attribute__((ext_vector_type(4)));
typedef unsigned short us4 __attribute__((ext_vector_type(4)));

__device__ __forceinline__ unsigned short f2bf(float f) {
  union { float f; unsigned u; } v; v.f = f;
  unsigned r = v.u + 0x7FFFu + ((v.u >> 16) & 1u);
  return (unsigned short)(r >> 16);
}

__device__ __forceinline__ void gload16(const void* g, void* l) {
  __builtin_amdgcn_global_load_lds(
      (const __attribute__((address_space(1))) void*)g,
      (__attribute__((address_space(3))) void*)l, 16, 0, 0);
}

// ---------------- x fp32 -> bf16 ----------------
__global__ void k_convert_x(const float* __restrict__ x, unsigned short* __restrict__ xb) {
  int i = (blockIdx.x * 256 + threadIdx.x) * 4;
  float4 v = *(const float4*)(x + i);
  us4 o;
  o[0] = f2bf(v.x); o[1] = f2bf(v.y); o[2] = f2bf(v.z); o[3] = f2bf(v.w);
  *(us4*)(xb + i) = o;
}

// -------- (E, rows, cols) fp32 -> (E, cols, rows) bf16 --------
__global__ void k_transpose_bf16(const float* __restrict__ in, unsigned short* __restrict__ out,
                                 int rows, int cols) {
  __shared__ float t[32][33];
  const float* ine = in + (size_t)blockIdx.z * rows * cols;
  unsigned short* oute = out + (size_t)blockIdx.z * rows * cols;
  int c0 = blockIdx.x * 32, r0 = blockIdx.y * 32;
  int tx = threadIdx.x, ty = threadIdx.y;
#pragma unroll
  for (int j = 0; j < 32; j += 8)
    t[ty + j][tx] = ine[(size_t)(r0 + ty + j) * cols + c0 + tx];
  __syncthreads();
#pragma unroll
  for (int j = 0; j < 32; j += 8)
    oute[(size_t)(c0 + ty + j) * rows + r0 + tx] = f2bf(t[tx][ty + j]);
}

// ---------------- router: logits, top-2, softmax ----------------
__global__ void k_router(const float* __restrict__ x, const float* __restrict__ wg,
                         const float* __restrict__ bg, int* __restrict__ tidx,
                         float* __restrict__ tgate, int* __restrict__ cnt) {
  int wid = threadIdx.x >> 6, lane = threadIdx.x & 63;
  int t = blockIdx.x * 4 + wid;
  float acc[E_NUM];
#pragma unroll
  for (int e = 0; e < E_NUM; e++) acc[e] = 0.f;
  const float* xr = x + (size_t)t * D_DIM;
  for (int i = lane; i < D_DIM; i += 64) {
    float xv = xr[i];
#pragma unroll
    for (int e = 0; e < E_NUM; e++) acc[e] += xv * wg[e * D_DIM + i];
  }
#pragma unroll
  for (int e = 0; e < E_NUM; e++) {
#pragma unroll
    for (int off = 32; off; off >>= 1) acc[e] += __shfl_xor(acc[e], off);
  }
  if (lane == 0) {
    float v[E_NUM];
#pragma unroll
    for (int e = 0; e < E_NUM; e++) v[e] = acc[e] + bg[e];
    int i0 = 0; float v0 = v[0];
#pragma unroll
    for (int e = 1; e < E_NUM; e++) if (v[e] > v0) { v0 = v[e]; i0 = e; }
    int i1 = -1; float v1 = -1e30f;
#pragma unroll
    for (int e = 0; e < E_NUM; e++) if (e != i0 && v[e] > v1) { v1 = v[e]; i1 = e; }
    float g0 = 1.f / (1.f + expf(v1 - v0));
    float g1 = 1.f - g0;
    tidx[2 * t] = i0; tidx[2 * t + 1] = i1;
    tgate[2 * t] = g0; tgate[2 * t + 1] = g1;
    atomicAdd(cnt + i0, 1);
    atomicAdd(cnt + i1, 1);
  }
}

__global__ void k_prefix(const int* __restrict__ cnt, int* __restrict__ eoff,
                         int* __restrict__ cursor) {
  if (threadIdx.x == 0) {
    int a = 0;
    for (int e = 0; e < E_NUM; e++) { eoff[e] = a; cursor[e] = a; a += cnt[e]; }
    eoff[E_NUM] = a;
  }
}

__global__ void k_scatter(const int* __restrict__ tidx, const float* __restrict__ tgate,
                          int* __restrict__ cursor, int* __restrict__ ptok,
                          float* __restrict__ pgate) {
  int t = blockIdx.x * 256 + threadIdx.x;
#pragma unroll
  for (int k = 0; k < 2; k++) {
    int e = tidx[2 * t + k];
    int p = atomicAdd(cursor + e, 1);
    ptok[p] = t;
    pgate[p] = tgate[2 * t + k];
  }
}

// ---------------- grouped GEMM, 256x256 tile, static double-buffer ----------
// LDS layout per 256x32 tile: 64B rows of 4x16B segs, swizzled
//   slot[row][s] = data[row][ s ^ ((row>>1)&3) ]   (2-way bank spread = free)
// realized via pre-swizzled GLOBAL source (gload_lds dest must stay linear).
// MODE 1: A = xb gathered via ptok, out = relu(A@B^T + b1) -> Hbuf (bf16)
// MODE 2: A = Hbuf rows direct,   out = (A@B^T + b2)*gate atomicAdd-> Out
template <int KDIM, int NDIM, int MODE>
__global__ __launch_bounds__(512, 1) void k_gemm(
    const unsigned short* __restrict__ A, const unsigned short* __restrict__ Bt,
    const float* __restrict__ bias, const int* __restrict__ eoff,
    const int* __restrict__ ptok, const float* __restrict__ pgate,
    unsigned short* __restrict__ Hout, float* __restrict__ Out) {
  constexpr int NT = NDIM / 256;
  constexpr int MT_MAX = NPAIR / 256;
  int nwg = gridDim.x;
  int bid = blockIdx.x;
  int tile = (bid & 7) * (nwg >> 3) + (bid >> 3);  // XCD chunk swizzle (nwg%8==0)
  int e = tile / (MT_MAX * NT);
  int rem = tile - e * (MT_MAX * NT);
  int mt = rem / NT;
  int nt = rem - mt * NT;
  int off = eoff[e];
  int cnt = eoff[e + 1] - off;
  int m0 = mt * 256;
  if (m0 >= cnt) return;

  __shared__ unsigned short lds[2][2][256 * 32];  // [buf][A/B][row][32 shorts]

  int tid = threadIdx.x;
  int w = tid >> 6, lane = tid & 63;
  int wm = w >> 2, wn = w & 3;  // 2 x 4 wave grid, each wave: 128 x 64 output

  // staging: chunk q = w*2+c covers rows q*16..q*16+15; lane -> row q*16+(lane>>2),
  // LDS slot seg (lane&3). Global source seg pre-swizzled: (lane&3)^((lane>>3)&3).
  int sseg = (lane & 3) ^ ((lane >> 3) & 3);
  const unsigned short* aSrc[2];
  const unsigned short* bSrc[2];
#pragma unroll
  for (int c = 0; c < 2; c++) {
    int q = w * 2 + c;
    int lrow = q * 16 + (lane >> 2);
    int arow = m0 + lrow;
    int ar = (arow < cnt) ? arow : (cnt - 1);
    size_t grow;
    if (MODE == 1) grow = (size_t)ptok[off + ar];
    else grow = (size_t)(off + ar);
    aSrc[c] = A + grow * KDIM + sseg * 8;
    int nrow = nt * 256 + q * 16 + (lane >> 2);
    bSrc[c] = Bt + (size_t)e * NDIM * KDIM + (size_t)nrow * KDIM + sseg * 8;
  }

  // fragment reads: row = base + (lane&15); wanted seg g = lane>>4;
  // read slot seg' = g ^ ((row>>1)&3) = (lane>>4) ^ ((lane>>1)&3) -- per-thread const.
  int segp = (lane >> 4) ^ ((lane >> 1) & 3);
  f32x4 acc[8][4] = {};

#define STAGE(buf, k0)                                          \
  {                                                             \
    _Pragma("unroll")                                           \
    for (int c = 0; c < 2; c++) {                               \
      int q = w * 2 + c;                                        \
      gload16(aSrc[c] + (k0), &lds[buf][0][q * 512]);           \
      gload16(bSrc[c] + (k0), &lds[buf][1][q * 512]);           \
    }                                                           \
  }

#define COMPUTE(buf)                                                        \
  {                                                                         \
    bf16x8 aF[8], bF[4];                                                    \
    _Pragma("unroll")                                                       \
    for (int m = 0; m < 8; m++) {                                           \
      int row = wm * 128 + m * 16 + (lane & 15);                            \
      aF[m] = *(const bf16x8*)&lds[buf][0][row * 32 + segp * 8];            \
    }                                                                       \
    _Pragma("unroll")                                                       \
    for (int n = 0; n < 4; n++) {                                           \
      int row = wn * 64 + n * 16 + (lane & 15);                             \
      bF[n] = *(const bf16x8*)&lds[buf][1][row * 32 + segp * 8];            \
    }                                                                       \
    _Pragma("unroll")                                                       \
    for (int m = 0; m < 8; m++)                                             \
      _Pragma("unroll")                                                     \
      for (int n = 0; n < 4; n++)                                           \
        acc[m][n] =                                                         \
            __builtin_amdgcn_mfma_f32_16x16x32_bf16(aF[m], bF[n], acc[m][n], 0, 0, 0); \
  }

  // prologue
  STAGE(0, 0);
  __syncthreads();
  int k0 = 0;
  // statically-unrolled double buffer: literal buffer indices, no runtime cur
  for (; k0 + 64 < KDIM; k0 += 64) {
    STAGE(1, k0 + 32);
    COMPUTE(0);
    __syncthreads();
    STAGE(0, k0 + 64);
    COMPUTE(1);
    __syncthreads();
  }
  // k0 == KDIM-64
  STAGE(1, k0 + 32);
  COMPUTE(0);
  __syncthreads();
  COMPUTE(1);

#undef STAGE
#undef COMPUTE

  // epilogue: C/D map col=lane&15, row=(lane>>4)*4+r
#pragma unroll
  for (int m = 0; m < 8; m++) {
    int lrowb = wm * 128 + m * 16 + (lane >> 4) * 4;
#pragma unroll
    for (int r = 0; r < 4; r++) {
      int arow = m0 + lrowb + r;
      if (arow < cnt) {
        if constexpr (MODE == 1) {
          size_t rowbase = (size_t)(off + arow) * NDIM;
#pragma unroll
          for (int n = 0; n < 4; n++) {
            int col = nt * 256 + wn * 64 + n * 16 + (lane & 15);
            float v = acc[m][n][r] + bias[e * NDIM + col];
            v = v > 0.f ? v : 0.f;
            Hout[rowbase + col] = f2bf(v);
          }
        } else {
          int tok = ptok[off + arow];
          float g = pgate[off + arow];
#pragma unroll
          for (int n = 0; n < 4; n++) {
            int col = nt * 256 + wn * 64 + n * 16 + (lane & 15);
            float v = (acc[m][n][r] + bias[e * NDIM + col]) * g;
            atomicAdd(Out + (size_t)tok * D_DIM + col, v);
          }
        }
      }
    }
  }
}

extern "C" void kernel_launch(void* const* d_in, const int* in_sizes, int n_in,
                              void* d_out, int out_size, void* d_ws, size_t ws_size,
                              hipStream_t stream) {
  const float* x  = (const float*)d_in[0];
  const float* wg = (const float*)d_in[1];
  const float* bg = (const float*)d_in[2];
  const float* w1 = (const float*)d_in[3];
  const float* b1 = (const float*)d_in[4];
  const float* w2 = (const float*)d_in[5];
  const float* b2 = (const float*)d_in[6];
  float* out = (float*)d_out;

  char* ws = (char*)d_ws;
  unsigned short* xb = (unsigned short*)ws;   ws += (size_t)B_TOK * D_DIM * 2;
  unsigned short* w1t = (unsigned short*)ws;  ws += (size_t)E_NUM * D_DIM * H_DIM * 2;
  unsigned short* w2t = (unsigned short*)ws;  ws += (size_t)E_NUM * D_DIM * H_DIM * 2;
  unsigned short* Hbuf = (unsigned short*)ws; ws += (size_t)NPAIR * H_DIM * 2;
  int* tidx = (int*)ws;    ws += (size_t)NPAIR * 4;
  float* tgate = (float*)ws; ws += (size_t)NPAIR * 4;
  int* ptok = (int*)ws;    ws += (size_t)NPAIR * 4;
  float* pgate = (float*)ws; ws += (size_t)NPAIR * 4;
  int* meta = (int*)ws;  // cnt[8] | eoff[9] | cursor[8]
  int* cnt = meta;
  int* eoff = meta + 8;
  int* cursor = meta + 17;

  hipMemsetAsync(meta, 0, 32 * sizeof(int), stream);
  hipMemsetAsync(out, 0, (size_t)out_size * sizeof(float), stream);

  k_convert_x<<<(B_TOK * D_DIM) / 1024, 256, 0, stream>>>(x, xb);
  dim3 tb(32, 8);
  k_transpose_bf16<<<dim3(H_DIM / 32, D_DIM / 32, E_NUM), tb, 0, stream>>>(w1, w1t, D_DIM, H_DIM);
  k_transpose_bf16<<<dim3(D_DIM / 32, H_DIM / 32, E_NUM), tb, 0, stream>>>(w2, w2t, H_DIM, D_DIM);
  k_router<<<B_TOK / 4, 256, 0, stream>>>(x, wg, bg, tidx, tgate, cnt);
  k_prefix<<<1, 64, 0, stream>>>(cnt, eoff, cursor);
  k_scatter<<<B_TOK / 256, 256, 0, stream>>>(tidx, tgate, cursor, ptok, pgate);
  k_gemm<D_DIM, H_DIM, 1><<<E_NUM * (NPAIR / 256) * (H_DIM / 256), 512, 0, stream>>>(
      xb, w1t, b1, eoff, ptok, pgate, Hbuf, nullptr);
  k_gemm<H_DIM, D_DIM, 2><<<E_NUM * (NPAIR / 256) * (D_DIM / 256), 512, 0, stream>>>(
      Hbuf, w2t, b2, eoff, ptok, pgate, nullptr, out);
}